// Round 7
// baseline (796.631 us; speedup 1.0000x reference)
//
#include <hip/hip_runtime.h>
#include <math.h>

// MAM dense: C[i,j] = max_k(A[i,k]*W[j,k]) + min_k(A[i,k]*W[j,k]) + bias[j]
// A = x flat [M=2048, K=768]; W [N=768, K=768] row-major; out [M,N] f32.
// fp16 packed inner loop (1 v_pk_mul_f16 + 1 v_pk_max_f16 + 1 v_pk_min_f16 per
// 2 products = algebraic floor). This round: A-fragment as single ds_read_b128
// (SAH=68 keeps 16B alignment), double-buffered LDS with ONE barrier per tile,
// issue-early/write-late staging. 768 blocks = 3/CU exact.

#define M_DIM 2048
#define N_DIM 768
#define K_DIM 768

#define BM 64
#define BN 32
#define BK 64
#define KP (BK / 2)            // 32 k-pair rows per tile
#define NTILES (K_DIM / BK)    // 12

// LDS strides in h2 (4B) units.
// SAH=68: byte row stride 272=16*17 -> b128 read at 4*(68*kk2+4*mt) always
// 16B-aligned; read = 4 distinct addrs/wave (16-way broadcast), conflict-free.
#define SAH 68
// SBH=34: b64 read at 8*(17*kk2+nt): 16 distinct addrs covering all 32 banks.
#define SBH 34

typedef _Float16 h2 __attribute__((ext_vector_type(2)));   // 4 B
typedef _Float16 h4 __attribute__((ext_vector_type(4)));   // 8 B
typedef _Float16 h8 __attribute__((ext_vector_type(8)));   // 16 B

__device__ __forceinline__ h2 cvt_pk(float x, float y) {
    return __builtin_bit_cast(h2, __builtin_amdgcn_cvt_pkrtz(x, y));
}

__global__ __launch_bounds__(256, 3) void mam_kernel(
    const float* __restrict__ A, const float* __restrict__ W,
    const float* __restrict__ bias, float* __restrict__ out)
{
    __shared__ __align__(16) h2 As[2][KP * SAH];   // [buf][kk2*SAH + m]
    __shared__ __align__(16) h2 Bs[2][KP * SBH];   // [buf][kk2*SBH + n]

    const int tid = threadIdx.x;
    const int m0 = blockIdx.y * BM;
    const int n0 = blockIdx.x * BN;
    const int mt = tid >> 4;   // 0..15 -> rows mt*4..mt*4+3
    const int nt = tid & 15;   // 0..15 -> cols nt*2..nt*2+1

    // running even-k / odd-k extrema, packed fp16
    h2 pmax[4][2], pmin[4][2];
    const _Float16 HMIN = (_Float16)(-65504.0f), HMAX = (_Float16)(65504.0f);
#pragma unroll
    for (int i = 0; i < 4; ++i)
#pragma unroll
        for (int j = 0; j < 2; ++j) {
            pmax[i][j] = (h2){HMIN, HMIN};
            pmin[i][j] = (h2){HMAX, HMAX};
        }

    // staging map: thread -> rows arow+16q, k-chunk akc (k = akc*4, kk2 = 2akc)
    const int arow = tid >> 4;
    const int akc  = tid & 15;
    const float* Ap = A + (size_t)m0 * K_DIM + akc * 4;
    const float* Wp = W + (size_t)n0 * K_DIM + akc * 4;

    const float bb0 = bias[n0 + nt * 2 + 0];
    const float bb1 = bias[n0 + nt * 2 + 1];

    float4 pa[4], pb[2];

    // issue tile t's global loads (f32, perfectly coalesced)
    auto gload = [&](int t) {
        const float* An = Ap + t * BK;
        const float* Wn = Wp + t * BK;
#pragma unroll
        for (int q = 0; q < 4; ++q)
            pa[q] = *(const float4*)(An + (size_t)(arow + 16 * q) * K_DIM);
#pragma unroll
        for (int q = 0; q < 2; ++q)
            pb[q] = *(const float4*)(Wn + (size_t)(arow + 16 * q) * K_DIM);
    };

    // convert f32->fp16 and write k-pair-interleaved into LDS buffer
    auto swrite = [&](h2* Asb, h2* Bsb) {
#pragma unroll
        for (int q = 0; q < 4; ++q) {
            Asb[(2 * akc + 0) * SAH + arow + 16 * q] = cvt_pk(pa[q].x, pa[q].y);
            Asb[(2 * akc + 1) * SAH + arow + 16 * q] = cvt_pk(pa[q].z, pa[q].w);
        }
#pragma unroll
        for (int q = 0; q < 2; ++q) {
            Bsb[(2 * akc + 0) * SBH + arow + 16 * q] = cvt_pk(pb[q].x, pb[q].y);
            Bsb[(2 * akc + 1) * SBH + arow + 16 * q] = cvt_pk(pb[q].z, pb[q].w);
        }
    };

    // compute 32 k-pair rows from one buffer (constant LDS offsets)
    auto compute = [&](const h2* Ab, const h2* Bb) {
#pragma unroll
        for (int kk2 = 0; kk2 < KP; ++kk2) {
            const h8 a = *(const h8*)(Ab + kk2 * SAH);   // one ds_read_b128: m0..m3 pairs
            const h4 b = *(const h4*)(Bb + kk2 * SBH);   // one ds_read_b64:  n0..n1 pairs
            const h2 am[4] = {__builtin_shufflevector(a, a, 0, 1),
                              __builtin_shufflevector(a, a, 2, 3),
                              __builtin_shufflevector(a, a, 4, 5),
                              __builtin_shufflevector(a, a, 6, 7)};
            const h2 bn[2] = {__builtin_shufflevector(b, b, 0, 1),
                              __builtin_shufflevector(b, b, 2, 3)};
#pragma unroll
            for (int i = 0; i < 4; ++i)
#pragma unroll
                for (int j = 0; j < 2; ++j) {
                    const h2 p = am[i] * bn[j];                             // v_pk_mul_f16
                    pmax[i][j] = __builtin_elementwise_max(pmax[i][j], p);  // v_pk_max_f16
                    pmin[i][j] = __builtin_elementwise_min(pmin[i][j], p);  // v_pk_min_f16
                }
        }
    };

    // prologue: tile 0 into buffer 0
    gload(0);
    swrite(As[0], Bs[0]);
    __syncthreads();

    const h2* Ard0 = &As[0][mt * 4];
    const h2* Ard1 = &As[1][mt * 4];
    const h2* Brd0 = &Bs[0][nt * 2];
    const h2* Brd1 = &Bs[1][nt * 2];

    // double-buffered main loop, unrolled x2, ONE barrier per tile
#pragma unroll 1
    for (int ktt = 0; ktt < NTILES / 2; ++ktt) {
        const int kt = 2 * ktt;
        // even step: compute buf0(tile kt), stage tile kt+1 -> buf1
        gload(kt + 1);                 // issue loads early (hide under compute)
        compute(Ard0, Brd0);
        swrite(As[1], Bs[1]);          // write late (loads have landed)
        __syncthreads();
        // odd step: compute buf1(tile kt+1), stage tile kt+2 -> buf0
        if (ktt < NTILES / 2 - 1) {
            gload(kt + 2);
            compute(Ard1, Brd1);
            swrite(As[0], Bs[0]);
            __syncthreads();
        } else {
            compute(Ard1, Brd1);       // last tile: nothing left to stage
        }
    }

    // epilogue: combine even/odd extrema, add bias, store f32
#pragma unroll
    for (int i = 0; i < 4; ++i) {
        float2 o;
        o.x = fmaxf((float)pmax[i][0].x, (float)pmax[i][0].y)
            + fminf((float)pmin[i][0].x, (float)pmin[i][0].y) + bb0;
        o.y = fmaxf((float)pmax[i][1].x, (float)pmax[i][1].y)
            + fminf((float)pmin[i][1].x, (float)pmin[i][1].y) + bb1;
        *(float2*)&out[(size_t)(m0 + mt * 4 + i) * N_DIM + n0 + nt * 2] = o;
    }
}

extern "C" void kernel_launch(void* const* d_in, const int* in_sizes, int n_in,
                              void* d_out, int out_size, void* d_ws, size_t ws_size,
                              hipStream_t stream) {
    const float* x    = (const float*)d_in[0];   // [2,1024,768] -> [2048,768]
    const float* w    = (const float*)d_in[1];   // [768,768] row-major [N][K]
    const float* bias = (const float*)d_in[2];   // [768]
    float* out = (float*)d_out;                  // [2048,768]

    dim3 grid(N_DIM / BN, M_DIM / BM);           // (24, 32) = 768 blocks = 3/CU
    mam_kernel<<<grid, 256, 0, stream>>>(x, w, bias, out);
}

// Round 8
// 69.292 us; speedup vs baseline: 11.4967x; 11.4967x over previous
//
#include <hip/hip_runtime.h>
#include <math.h>

// MAM dense: C[i,j] = max_k(A[i,k]*W[j,k]) + min_k(A[i,k]*W[j,k]) + bias[j]
// A = x flat [M=2048, K=768]; W [N=768, K=768] row-major; out [M,N] f32.
// fp16 packed inner loop (v_pk_mul/max/min_f16 = 3 VALU per 2 products).
// Double-buffered LDS, ONE barrier per tile, issue-early/write-late staging.
// R7 lesson: NO lambdas / no reference-captured register arrays (they escape
// to scratch -> 115 MB of spill traffic). Macros + named float4 regs instead.

#define M_DIM 2048
#define N_DIM 768
#define K_DIM 768

#define BM 64
#define BN 32
#define BK 64
#define KP (BK / 2)            // 32 k-pair rows per tile
#define NTILES (K_DIM / BK)    // 12

// LDS strides in h2 (4B) units.
// SAH=68: byte row stride 272 -> b128 A-read at 4*(68*kk2+4*mt) is 16B-aligned;
// 4 distinct addrs/wave (16-way broadcast), conflict-free.
#define SAH 68
// SBH=34: b64 B-read: 16 distinct addrs covering all 32 banks once.
#define SBH 34

typedef _Float16 h2 __attribute__((ext_vector_type(2)));   // 4 B
typedef _Float16 h4 __attribute__((ext_vector_type(4)));   // 8 B
typedef _Float16 h8 __attribute__((ext_vector_type(8)));   // 16 B

__device__ __forceinline__ h2 cvt_pk(float x, float y) {
    return __builtin_bit_cast(h2, __builtin_amdgcn_cvt_pkrtz(x, y));
}

__global__ __launch_bounds__(256, 3) void mam_kernel(
    const float* __restrict__ A, const float* __restrict__ W,
    const float* __restrict__ bias, float* __restrict__ out)
{
    __shared__ __align__(16) h2 As[2][KP * SAH];
    __shared__ __align__(16) h2 Bs[2][KP * SBH];

    const int tid = threadIdx.x;
    const int m0 = blockIdx.y * BM;
    const int n0 = blockIdx.x * BN;
    const int mt = tid >> 4;   // 0..15 -> rows mt*4..mt*4+3
    const int nt = tid & 15;   // 0..15 -> cols nt*2..nt*2+1

    h2 pmax[4][2], pmin[4][2];
    const _Float16 HMIN = (_Float16)(-65504.0f), HMAX = (_Float16)(65504.0f);
#pragma unroll
    for (int i = 0; i < 4; ++i)
#pragma unroll
        for (int j = 0; j < 2; ++j) {
            pmax[i][j] = (h2){HMIN, HMIN};
            pmin[i][j] = (h2){HMAX, HMAX};
        }

    // staging map: thread covers rows arow+16q (q=0..), k-chunk akc (kk2=2*akc)
    const int arow = tid >> 4;
    const int akc  = tid & 15;
    const float* Ap = A + (size_t)(m0 + arow) * K_DIM + akc * 4;
    const float* Wp = W + (size_t)(n0 + arow) * K_DIM + akc * 4;  // arow<32 rows for B handled by q loop

    const float bb0 = bias[n0 + nt * 2 + 0];
    const float bb1 = bias[n0 + nt * 2 + 1];

    float4 pa0, pa1, pa2, pa3, pb0, pb1;

#define GLOAD(t) do {                                                        \
        const float* An_ = Ap + (t) * BK;                                    \
        const float* Wn_ = Wp + (t) * BK;                                    \
        pa0 = *(const float4*)(An_ + (size_t)( 0) * K_DIM);                  \
        pa1 = *(const float4*)(An_ + (size_t)(16) * K_DIM);                  \
        pa2 = *(const float4*)(An_ + (size_t)(32) * K_DIM);                  \
        pa3 = *(const float4*)(An_ + (size_t)(48) * K_DIM);                  \
        pb0 = *(const float4*)(Wn_ + (size_t)( 0) * K_DIM);                  \
        pb1 = *(const float4*)(Wn_ + (size_t)(16) * K_DIM);                  \
    } while (0)

#define SWRITE(buf) do {                                                     \
        h2* Aw_ = &As[buf][2 * akc * SAH + arow];                            \
        Aw_[0]            = cvt_pk(pa0.x, pa0.y);                            \
        Aw_[SAH]          = cvt_pk(pa0.z, pa0.w);                            \
        Aw_[16]           = cvt_pk(pa1.x, pa1.y);                            \
        Aw_[SAH + 16]     = cvt_pk(pa1.z, pa1.w);                            \
        Aw_[32]           = cvt_pk(pa2.x, pa2.y);                            \
        Aw_[SAH + 32]     = cvt_pk(pa2.z, pa2.w);                            \
        Aw_[48]           = cvt_pk(pa3.x, pa3.y);                            \
        Aw_[SAH + 48]     = cvt_pk(pa3.z, pa3.w);                            \
        h2* Bw_ = &Bs[buf][2 * akc * SBH + arow];                            \
        Bw_[0]            = cvt_pk(pb0.x, pb0.y);                            \
        Bw_[SBH]          = cvt_pk(pb0.z, pb0.w);                            \
        Bw_[16]           = cvt_pk(pb1.x, pb1.y);                            \
        Bw_[SBH + 16]     = cvt_pk(pb1.z, pb1.w);                            \
    } while (0)

#define COMPUTE(buf) do {                                                    \
        const h2* Ab_ = &As[buf][mt * 4];                                    \
        const h2* Bb_ = &Bs[buf][nt * 2];                                    \
        _Pragma("unroll")                                                    \
        for (int kk2 = 0; kk2 < KP; ++kk2) {                                 \
            const h8 a_ = *(const h8*)(Ab_ + kk2 * SAH);                     \
            const h4 b_ = *(const h4*)(Bb_ + kk2 * SBH);                     \
            const h2 am0 = __builtin_shufflevector(a_, a_, 0, 1);            \
            const h2 am1 = __builtin_shufflevector(a_, a_, 2, 3);            \
            const h2 am2 = __builtin_shufflevector(a_, a_, 4, 5);            \
            const h2 am3 = __builtin_shufflevector(a_, a_, 6, 7);            \
            const h2 bn0 = __builtin_shufflevector(b_, b_, 0, 1);            \
            const h2 bn1 = __builtin_shufflevector(b_, b_, 2, 3);            \
            h2 p_;                                                           \
            p_ = am0 * bn0; pmax[0][0] = __builtin_elementwise_max(pmax[0][0], p_); pmin[0][0] = __builtin_elementwise_min(pmin[0][0], p_); \
            p_ = am0 * bn1; pmax[0][1] = __builtin_elementwise_max(pmax[0][1], p_); pmin[0][1] = __builtin_elementwise_min(pmin[0][1], p_); \
            p_ = am1 * bn0; pmax[1][0] = __builtin_elementwise_max(pmax[1][0], p_); pmin[1][0] = __builtin_elementwise_min(pmin[1][0], p_); \
            p_ = am1 * bn1; pmax[1][1] = __builtin_elementwise_max(pmax[1][1], p_); pmin[1][1] = __builtin_elementwise_min(pmin[1][1], p_); \
            p_ = am2 * bn0; pmax[2][0] = __builtin_elementwise_max(pmax[2][0], p_); pmin[2][0] = __builtin_elementwise_min(pmin[2][0], p_); \
            p_ = am2 * bn1; pmax[2][1] = __builtin_elementwise_max(pmax[2][1], p_); pmin[2][1] = __builtin_elementwise_min(pmin[2][1], p_); \
            p_ = am3 * bn0; pmax[3][0] = __builtin_elementwise_max(pmax[3][0], p_); pmin[3][0] = __builtin_elementwise_min(pmin[3][0], p_); \
            p_ = am3 * bn1; pmax[3][1] = __builtin_elementwise_max(pmax[3][1], p_); pmin[3][1] = __builtin_elementwise_min(pmin[3][1], p_); \
        }                                                                    \
    } while (0)

    // prologue: tile 0 -> buf 0
    GLOAD(0);
    SWRITE(0);
    __syncthreads();

    // main loop: 5 iterations cover tiles 0..9; one barrier per tile
#pragma unroll 1
    for (int ktt = 0; ktt < NTILES / 2 - 1; ++ktt) {
        GLOAD(2 * ktt + 1);        // issue early: latency hides under compute
        COMPUTE(0);
        SWRITE(1);                 // write late: loads have landed
        __syncthreads();
        GLOAD(2 * ktt + 2);
        COMPUTE(1);
        SWRITE(0);
        __syncthreads();
    }
    // peeled tail: tile 10 (buf0) while staging tile 11, then tile 11 (buf1)
    GLOAD(NTILES - 1);
    COMPUTE(0);
    SWRITE(1);
    __syncthreads();
    COMPUTE(1);

    // epilogue: combine even/odd extrema, add bias, store f32
#pragma unroll
    for (int i = 0; i < 4; ++i) {
        float2 o;
        o.x = fmaxf((float)pmax[i][0].x, (float)pmax[i][0].y)
            + fminf((float)pmin[i][0].x, (float)pmin[i][0].y) + bb0;
        o.y = fmaxf((float)pmax[i][1].x, (float)pmax[i][1].y)
            + fminf((float)pmin[i][1].x, (float)pmin[i][1].y) + bb1;
        *(float2*)&out[(size_t)(m0 + mt * 4 + i) * N_DIM + n0 + nt * 2] = o;
    }
}

extern "C" void kernel_launch(void* const* d_in, const int* in_sizes, int n_in,
                              void* d_out, int out_size, void* d_ws, size_t ws_size,
                              hipStream_t stream) {
    const float* x    = (const float*)d_in[0];   // [2,1024,768] -> [2048,768]
    const float* w    = (const float*)d_in[1];   // [768,768] row-major [N][K]
    const float* bias = (const float*)d_in[2];   // [768]
    float* out = (float*)d_out;                  // [2048,768]

    dim3 grid(N_DIM / BN, M_DIM / BM);           // (24, 32) = 768 blocks = 3/CU
    mam_kernel<<<grid, 256, 0, stream>>>(x, w, bias, out);
}